// Round 1
// baseline (1720.677 us; speedup 1.0000x reference)
//
#include <hip/hip_runtime.h>

// RNNBlock: h_t = relu(x_t @ W + h_{t-1} @ U + b) over reversed T, then
// out = relu(h @ W1 + b1).  B=65536, T=79, F=8, C=DW=256.
//
// Design: wg = 64 batch rows, 4 waves; wave owns 64 output channels.
// U (and W,b; later W1,b1) live as register-resident MFMA B-fragments with
// K augmented to 272 = 256 (h) + 8 (x) + 1 (bias=1.0 slot) + 7 (zero).
// h exchanged across waves via double-buffered LDS fp16 (XOR-swizzled,
// 1 barrier/step). MFMA: v_mfma_f32_32x32x16_f16.
//
// Layouts (cdna4_isa / learn_hip verified for 32x32 shape):
//   A[m][k]: m = lane&31, k = 8*(lane>>5) + j   (j=0..7, half8)
//   B[k][n]: k = 8*(lane>>5) + j, n = lane&31
//   C/D    : col = lane&31, row = (reg&3) + 8*(reg>>2) + 4*(lane>>5)

#define B_ROWS 65536
#define T_STEPS 79
#define F_IN 8
#define C_DIM 256

typedef _Float16 h16;
typedef __attribute__((ext_vector_type(4))) _Float16 half4;
typedef __attribute__((ext_vector_type(8))) _Float16 half8;
typedef __attribute__((ext_vector_type(16))) float f32x16;
typedef __attribute__((ext_vector_type(4))) float f32x4;

// Load B-fragments for a 272x256 augmented weight: rows 0..255 = M (U or W1),
// rows 256..263 = Wx (x kernel, or zeros), row 264 = bias, rows 265..271 = 0.
// ncb = this wave's first output column.
__device__ __forceinline__ void load_bfrags(half8 bf[17][2],
                                            const float* __restrict__ M,
                                            const float* __restrict__ Wx,
                                            const float* __restrict__ bias,
                                            int ncb, int l31, int q) {
  #pragma unroll
  for (int kf = 0; kf < 16; ++kf) {
    const int k0 = 16 * kf + 8 * q;
    #pragma unroll
    for (int nf = 0; nf < 2; ++nf) {
      const int n = ncb + 32 * nf + l31;
      half8 v;
      #pragma unroll
      for (int j = 0; j < 8; ++j)
        v[j] = (h16)M[(size_t)(k0 + j) * C_DIM + n];
      bf[kf][nf] = v;
    }
  }
  // augmented K-fragment (kf = 16): k = 256 + 8q + j
  #pragma unroll
  for (int nf = 0; nf < 2; ++nf) {
    const int n = ncb + 32 * nf + l31;
    half8 v;
    #pragma unroll
    for (int j = 0; j < 8; ++j) v[j] = (h16)0.f;
    if (q == 0) {
      if (Wx) {
        #pragma unroll
        for (int j = 0; j < 8; ++j) v[j] = (h16)Wx[j * C_DIM + n];
      }
    } else {
      v[0] = (h16)bias[n];  // k = 264 pairs with A-side constant 1.0
    }
    bf[16][nf] = v;
  }
}

// LDS address for h[r][c], r in [0,64), c in [0,256), fp16, XOR-swizzled at
// 8-byte granules so strided A-frag reads are ~conflict-free at 64KB total.
__device__ __forceinline__ int lds_addr(int r, int c) {
  const int g = (c >> 2) ^ (r & 15);
  return r * 256 + (g << 2) + (c & 3);
}

__global__ __launch_bounds__(256, 2)
void rnn_fused(const float* __restrict__ x, const float* __restrict__ W,
               const float* __restrict__ U, const float* __restrict__ b,
               const float* __restrict__ W1, const float* __restrict__ b1,
               float* __restrict__ out) {
  __shared__ h16 hbuf[2][64 * 256];  // 64 KB double-buffered h exchange

  const int tid = threadIdx.x;
  const int lane = tid & 63;
  const int wave = tid >> 6;      // 0..3, owns cols [64w, 64w+64)
  const int l31 = lane & 31;
  const int q = lane >> 5;
  const int row0 = blockIdx.x << 6;  // first batch row of this wg
  const int ncb = wave << 6;

  half8 bf[17][2];
  load_bfrags(bf, U, W, b, ncb, l31, q);

  int buf = 0;
  #pragma unroll 1
  for (int s = 0; s < T_STEPS; ++s) {
    // ---- augmented A fragment: lanes q==0 carry x_t (8 floats -> fp16),
    //      lanes q==1 carry [1,0,...] (bias slot). Load before the barrier.
    const int t = T_STEPS - 1 - s;  // go_backwards
    half8 xa[2];
    #pragma unroll
    for (int mf = 0; mf < 2; ++mf) {
      half8 v;
      if (q == 0) {
        const float* xp = x + (size_t)(row0 + 32 * mf + l31) * (T_STEPS * F_IN)
                            + (size_t)t * F_IN;
        const f32x4* xp4 = (const f32x4*)xp;
        const f32x4 lo = xp4[0], hi = xp4[1];
        v[0] = (h16)lo[0]; v[1] = (h16)lo[1]; v[2] = (h16)lo[2]; v[3] = (h16)lo[3];
        v[4] = (h16)hi[0]; v[5] = (h16)hi[1]; v[6] = (h16)hi[2]; v[7] = (h16)hi[3];
      } else {
        #pragma unroll
        for (int j = 0; j < 8; ++j) v[j] = (h16)0.f;
        v[0] = (h16)1.f;
      }
      xa[mf] = v;
    }

    __syncthreads();  // h (step s-1) writes visible in hbuf[buf]

    // init acc with the augmented MFMA (x@W + b)
    f32x16 acc[2][2];
    #pragma unroll
    for (int mf = 0; mf < 2; ++mf)
      #pragma unroll
      for (int nf = 0; nf < 2; ++nf)
        acc[mf][nf] = __builtin_amdgcn_mfma_f32_32x32x16_f16(
            xa[mf], bf[16][nf], (f32x16)(0.f), 0, 0, 0);

    if (s > 0) {  // h_0 = 0: skip the h@U part on the first step
      const h16* hb = hbuf[buf];
      #pragma unroll
      for (int kf = 0; kf < 16; ++kf) {
        #pragma unroll
        for (int mf = 0; mf < 2; ++mf) {
          const int r = 32 * mf + l31;
          const int c0 = 16 * kf + 8 * q;
          const half4 lo = *(const half4*)&hb[lds_addr(r, c0)];
          const half4 hi = *(const half4*)&hb[lds_addr(r, c0 + 4)];
          const half8 a = {lo[0], lo[1], lo[2], lo[3],
                           hi[0], hi[1], hi[2], hi[3]};
          #pragma unroll
          for (int nf = 0; nf < 2; ++nf)
            acc[mf][nf] = __builtin_amdgcn_mfma_f32_32x32x16_f16(
                a, bf[kf][nf], acc[mf][nf], 0, 0, 0);
        }
      }
    }

    // ---- epilogue: relu -> fp16 -> other LDS buffer
    h16* hn = hbuf[buf ^ 1];
    #pragma unroll
    for (int mf = 0; mf < 2; ++mf) {
      #pragma unroll
      for (int nf = 0; nf < 2; ++nf) {
        #pragma unroll
        for (int reg = 0; reg < 16; ++reg) {
          float v = fmaxf(acc[mf][nf][reg], 0.f);
          const int rr = (reg & 3) + ((reg >> 2) << 3) + (q << 2) + (mf << 5);
          const int cc = ncb + (nf << 5) + l31;
          hn[lds_addr(rr, cc)] = (h16)v;
        }
      }
    }
    buf ^= 1;
  }

  // ---- final Dense(256, relu): identical GEMM step with W1/b1, no x rows
  load_bfrags(bf, W1, nullptr, b1, ncb, l31, q);
  half8 xa;
  #pragma unroll
  for (int j = 0; j < 8; ++j) xa[j] = (h16)0.f;
  if (q == 1) xa[0] = (h16)1.f;

  __syncthreads();

  f32x16 acc[2][2];
  #pragma unroll
  for (int mf = 0; mf < 2; ++mf)
    #pragma unroll
    for (int nf = 0; nf < 2; ++nf)
      acc[mf][nf] = __builtin_amdgcn_mfma_f32_32x32x16_f16(
          xa, bf[16][nf], (f32x16)(0.f), 0, 0, 0);

  {
    const h16* hb = hbuf[buf];
    #pragma unroll
    for (int kf = 0; kf < 16; ++kf) {
      #pragma unroll
      for (int mf = 0; mf < 2; ++mf) {
        const int r = 32 * mf + l31;
        const int c0 = 16 * kf + 8 * q;
        const half4 lo = *(const half4*)&hb[lds_addr(r, c0)];
        const half4 hi = *(const half4*)&hb[lds_addr(r, c0 + 4)];
        const half8 a = {lo[0], lo[1], lo[2], lo[3],
                         hi[0], hi[1], hi[2], hi[3]};
        #pragma unroll
        for (int nf = 0; nf < 2; ++nf)
          acc[mf][nf] = __builtin_amdgcn_mfma_f32_32x32x16_f16(
              a, bf[kf][nf], acc[mf][nf], 0, 0, 0);
      }
    }
  }

  #pragma unroll
  for (int mf = 0; mf < 2; ++mf) {
    #pragma unroll
    for (int nf = 0; nf < 2; ++nf) {
      #pragma unroll
      for (int reg = 0; reg < 16; ++reg) {
        const float v = fmaxf(acc[mf][nf][reg], 0.f);
        const int rr = (reg & 3) + ((reg >> 2) << 3) + (q << 2) + (mf << 5);
        const int cc = ncb + (nf << 5) + l31;
        out[(size_t)(row0 + rr) * C_DIM + cc] = v;
      }
    }
  }
}

extern "C" void kernel_launch(void* const* d_in, const int* in_sizes, int n_in,
                              void* d_out, int out_size, void* d_ws, size_t ws_size,
                              hipStream_t stream) {
  const float* x  = (const float*)d_in[0];
  const float* W  = (const float*)d_in[1];
  const float* U  = (const float*)d_in[2];
  const float* b  = (const float*)d_in[3];
  const float* W1 = (const float*)d_in[4];
  const float* b1 = (const float*)d_in[5];
  float* out = (float*)d_out;

  rnn_fused<<<B_ROWS / 64, 256, 0, stream>>>(x, W, U, b, W1, b1, out);
}